// Round 11
// baseline (363.663 us; speedup 1.0000x reference)
//
#include <hip/hip_runtime.h>
#include <math.h>

typedef unsigned short u16;
typedef unsigned int   u32;
typedef __attribute__((ext_vector_type(8))) __bf16 bf16x8;
typedef __attribute__((ext_vector_type(4))) float  f32x4;

#define BB 16
#define LL 2048
#define DD 512
#define NF 1025
#define TOPK 4

// ws layout (float-unit offsets), total ~136 MB (XC slot now unused)
static const size_t OFF_XB  = 0;                         // bf16 x row-major [B*L][D]
static const size_t OFF_XTB = OFF_XB  + 8388608;         // bf16 x transposed [B][D][L]
static const size_t OFF_GTB = OFF_XTB + 8388608;         // bf16 G transposed [B][D][L]
static const size_t OFF_XC  = OFF_GTB + 8388608;         // (unused since R11 fusion)
static const size_t OFF_BBM = OFF_XC  + 8388608;         // bf16 Bmat [1024][512]: 0..511=M, 512..1023=Wv
static const size_t OFF_S   = OFF_BBM + 262144;          // spectra [B][NF][2]
static const size_t OFF_W   = OFF_S   + (size_t)BB * NF * 2;
static const size_t OFF_I   = OFF_W   + BB * TOPK;

__device__ __forceinline__ u16 f2bf(float f) {
    u32 u = __float_as_uint(f);
    return (u16)((u + 0x7fffu + ((u >> 16) & 1u)) >> 16);
}
__device__ __forceinline__ float bf2f(u16 h) {
    return __uint_as_float(((u32)h) << 16);
}
__device__ __forceinline__ void gload16(const void* g, void* l) {
    __builtin_amdgcn_global_load_lds((const __attribute__((address_space(1))) void*)g,
                                     (__attribute__((address_space(3))) void*)l, 16, 0, 0);
}
__device__ __forceinline__ float2 cmul(float2 u, float2 v) {
    return make_float2(u.x * v.x - u.y * v.y, u.x * v.y + u.y * v.x);
}
__device__ __forceinline__ float2 cadd(float2 u, float2 v) { return make_float2(u.x + v.x, u.y + v.y); }
__device__ __forceinline__ float2 csub(float2 u, float2 v) { return make_float2(u.x - v.x, u.y - v.y); }

// Bank-conflict-reducing padded index (1 pad per 8 float2).
__device__ __forceinline__ int P(int i) { return i + (i >> 3); }

// ---------------------------------------------------------------------------
// Radix-4 Stockham stage (R4/R5-verified math). NT = threads, TS = twiddle
// table shift (table holds W^{j<<TS}; all jm for the stages used are multiples
// of 1<<TS). M=512 has jm==0 -> identity, specialized.
template<int M, int SGN, int NT, int TS>
__device__ __forceinline__ void radix4(const float2* __restrict__ src,
                                       float2* __restrict__ dst,
                                       const float2* __restrict__ twl, int tid) {
#pragma unroll
    for (int r = 0; r < 512 / NT; r++) {
        int w = tid + NT * r;
        int k = w & (M - 1);
        int jm = w - k;
        float2 a = src[P(w)], b = src[P(w + 512)], c = src[P(w + 1024)], d = src[P(w + 1536)];
        float2 t0 = cadd(a, c), t1 = csub(a, c), t2 = cadd(b, d), bd = csub(b, d);
        float2 t3 = (SGN > 0) ? make_float2(bd.y, -bd.x)
                              : make_float2(-bd.y, bd.x);
        int o = 4 * jm + k;
        if (M == 512) {
            dst[P(o)]         = cadd(t0, t2);
            dst[P(o + M)]     = cadd(t1, t3);
            dst[P(o + 2 * M)] = csub(t0, t2);
            dst[P(o + 3 * M)] = csub(t1, t3);
        } else {
            float2 T1 = twl[jm >> TS];
            float2 T2 = cmul(T1, T1);
            float2 T3 = cmul(T1, T2);
            dst[P(o)]         = cadd(t0, t2);
            dst[P(o + M)]     = cmul(cadd(t1, t3), T1);
            dst[P(o + 2 * M)] = cmul(csub(t0, t2), T2);
            dst[P(o + 3 * M)] = cmul(csub(t1, t3), T3);
        }
    }
}

// ---------------------------------------------------------------------------
// Merged prologue (R8-proven; R9's split regressed +15us).
//   bid 0..63      : gemm1 M = Wq^T*Wk
//   bid 64..319    : cast Wv + zero S
//   bid 320..2367  : transpose x -> XTB (32d x 256t tiles)
//   bid 2368..10559: streaming cast x -> XB (linear)
__global__ __launch_bounds__(256) void k_pre(const float* __restrict__ x,
                                             const float* __restrict__ Wq,
                                             const float* __restrict__ Wk,
                                             const float* __restrict__ Wv,
                                             u16* __restrict__ xb,
                                             u16* __restrict__ xtb,
                                             u16* __restrict__ Bm,
                                             float* __restrict__ S) {
    __shared__ char sh[16768];
    int bid = blockIdx.x;
    int tid = threadIdx.x;
    if (bid < 64) {
        // ---- gemm1 branch: M = Wq^T * Wk -> bf16 rows 0..511 of Bmat
        int g = bid;
        float (*As)[68] = (float(*)[68])sh;
        float (*Bs)[68] = (float(*)[68])(sh + 4352);
        int tx = tid & 15, ty = tid >> 4;
        int m0 = (g & 7) * 64, n0 = (g >> 3) * 64;
        float acc[4][4] = {};
        for (int k0 = 0; k0 < DD; k0 += 16) {
#pragma unroll
            for (int r = 0; r < 4; r++) {
                As[ty][tx + 16 * r] = Wq[(size_t)(k0 + ty) * DD + m0 + tx + 16 * r];
                Bs[ty][tx + 16 * r] = Wk[(size_t)(k0 + ty) * DD + n0 + tx + 16 * r];
            }
            __syncthreads();
#pragma unroll
            for (int k = 0; k < 16; k++) {
                float4 a4 = *(const float4*)&As[k][ty * 4];
                float4 b4 = *(const float4*)&Bs[k][tx * 4];
                float a[4] = {a4.x, a4.y, a4.z, a4.w};
                float b[4] = {b4.x, b4.y, b4.z, b4.w};
#pragma unroll
                for (int i = 0; i < 4; i++)
#pragma unroll
                    for (int j = 0; j < 4; j++) acc[i][j] += a[i] * b[j];
            }
            __syncthreads();
        }
#pragma unroll
        for (int i = 0; i < 4; i++) {
            uint2 o;
            o.x = (u32)f2bf(acc[i][0]) | ((u32)f2bf(acc[i][1]) << 16);
            o.y = (u32)f2bf(acc[i][2]) | ((u32)f2bf(acc[i][3]) << 16);
            *(uint2*)&Bm[(size_t)(m0 + ty * 4 + i) * DD + n0 + tx * 4] = o;
        }
    } else if (bid < 320) {
        // ---- misc branch: cast Wv (rows 512..1023 of Bmat), zero S
        int g = bid - 64;                    // 0..255
        int i4 = g * 256 + tid;              // float4 index over 512*512
        float4 w = ((const float4*)Wv)[i4];
        ushort4 o;
        o.x = f2bf(w.x); o.y = f2bf(w.y); o.z = f2bf(w.z); o.w = f2bf(w.w);
        ((ushort4*)(Bm + DD * DD))[i4] = o;
        if (i4 < 8200)                       // 32800 floats = 8200 float4
            ((float4*)S)[i4] = make_float4(0.f, 0.f, 0.f, 0.f);
    } else if (bid < 2368) {
        // ---- transpose branch: x fp32 -> XTB bf16 [b][d][t], 32d x 256t tile.
        int tb = bid - 320;                  // 0..2047
        int bx = tb & 15;                    // d-tile (16 x 32)
        int by = (tb >> 4) & 7;              // t-tile (8 x 256)
        int bz = tb >> 7;                    // batch
        u32* tile32 = (u32*)sh;              // [32][131] u32 = 16768 B
        int tx = tid & 7, ty = tid >> 3;     // tx: d-quad, ty: 0..31
        int d0 = bx * 32, t0 = by * 256;
        const float* ip = x + ((size_t)bz * LL + t0) * DD + d0 + tx * 4;
        float4 va[4], vb[4];
#pragma unroll
        for (int ii = 0; ii < 4; ii++) {
            int h = ty + 32 * ii;
            va[ii] = *(const float4*)&ip[(size_t)(2 * h) * DD];
            vb[ii] = *(const float4*)&ip[(size_t)(2 * h + 1) * DD];
        }
#pragma unroll
        for (int ii = 0; ii < 4; ii++) {
            int h = ty + 32 * ii;
            u32 a0 = f2bf(va[ii].x), a1 = f2bf(va[ii].y), a2 = f2bf(va[ii].z), a3 = f2bf(va[ii].w);
            u32 b0 = f2bf(vb[ii].x), b1 = f2bf(vb[ii].y), b2 = f2bf(vb[ii].z), b3 = f2bf(vb[ii].w);
            tile32[(4 * tx + 0) * 131 + h] = a0 | (b0 << 16);
            tile32[(4 * tx + 1) * 131 + h] = a1 | (b1 << 16);
            tile32[(4 * tx + 2) * 131 + h] = a2 | (b2 << 16);
            tile32[(4 * tx + 3) * 131 + h] = a3 | (b3 << 16);
        }
        __syncthreads();
        u16* xtp = xtb + ((size_t)bz * DD + d0) * LL + t0;
#pragma unroll
        for (int u = 0; u < 4; u++) {
            int idx = u * 256 + tid;         // 0..1023
            int dr = idx >> 5;               // d row 0..31
            int ch = idx & 31;               // 16 B chunk within 512 B row
            const u32* rp = tile32 + dr * 131 + ch * 4;
            uint4 o = make_uint4(rp[0], rp[1], rp[2], rp[3]);
            *(uint4*)&xtp[(size_t)dr * LL + ch * 8] = o;
        }
    } else {
        // ---- streaming cast branch: x fp32 -> XB bf16, linear walk.
        size_t g = (size_t)(bid - 2368) * 256 + tid;   // uint4 index over XB
        const float4* x4 = (const float4*)x;
        float4 a = x4[2 * g], b = x4[2 * g + 1];
        uint4 o;
        o.x = (u32)f2bf(a.x) | ((u32)f2bf(a.y) << 16);
        o.y = (u32)f2bf(a.z) | ((u32)f2bf(a.w) << 16);
        o.z = (u32)f2bf(b.x) | ((u32)f2bf(b.y) << 16);
        o.w = (u32)f2bf(b.z) | ((u32)f2bf(b.w) << 16);
        ((uint4*)xb)[g] = o;
    }
}

// ---------------------------------------------------------------------------
// G = XB * M^T (bf16 MFMA), written transposed bf16 GTB[b][d][t].
__global__ __launch_bounds__(256, 2) void k_gemm2(const u16* __restrict__ Ab,
                                                  const u16* __restrict__ Bm,
                                                  u16* __restrict__ GTB) {
    __shared__ u16 smem[16384];
    u16* As = smem;
    u16* Bs = smem + 8192;
    int t = threadIdx.x;
    int wave = t >> 6, lane = t & 63;
    int l15 = lane & 15, l4 = lane >> 4;
    int qr = wave & 1, qc = wave >> 1;
    int m0 = blockIdx.x * 128, n0 = blockIdx.y * 128;

    f32x4 acc[4][4];
#pragma unroll
    for (int i = 0; i < 4; i++)
#pragma unroll
        for (int j = 0; j < 4; j++) acc[i][j] = (f32x4){0.f, 0.f, 0.f, 0.f};

    const u16* Ag = Ab + (size_t)m0 * DD;
    const u16* Bg = Bm + (size_t)n0 * DD;
    int a_base = (qr * 64 + l15) * 64 + l4 * 8;
    int b_base = (qc * 64 + l15) * 64 + l4 * 8;

    for (int k0 = 0; k0 < DD; k0 += 64) {
#pragma unroll
        for (int n = 0; n < 4; n++) {
            int c = wave * 256 + n * 64 + lane;
            int row = c >> 3, col = (c & 7) * 8;
            gload16(Ag + (size_t)row * DD + k0 + col, (char*)As + (size_t)(wave * 256 + n * 64) * 16);
            gload16(Bg + (size_t)row * DD + k0 + col, (char*)Bs + (size_t)(wave * 256 + n * 64) * 16);
        }
        __syncthreads();
#pragma unroll
        for (int kk = 0; kk < 64; kk += 32) {
            bf16x8 af[4], bq[4];
#pragma unroll
            for (int i = 0; i < 4; i++) af[i] = *(const bf16x8*)(As + a_base + i * 1024 + kk);
#pragma unroll
            for (int j = 0; j < 4; j++) bq[j] = *(const bf16x8*)(Bs + b_base + j * 1024 + kk);
#pragma unroll
            for (int i = 0; i < 4; i++)
#pragma unroll
                for (int j = 0; j < 4; j++)
                    acc[i][j] = __builtin_amdgcn_mfma_f32_16x16x32_bf16(af[i], bq[j], acc[i][j], 0, 0, 0);
        }
        __syncthreads();
    }

    // Epilogue: transposed bf16 write via swizzled LDS staging
    float4* tb4 = (float4*)smem;
    int bidx = m0 >> 11;
    int tbase = m0 & 2047;
#pragma unroll
    for (int p = 0; p < 2; p++) {
        __syncthreads();
        if (qc == p) {
#pragma unroll
            for (int j = 0; j < 4; j++) {
                int nloc = j * 16 + l15;
#pragma unroll
                for (int i = 0; i < 4; i++) {
                    int tq = qr * 16 + i * 4 + l4;
                    tb4[nloc * 32 + (tq ^ (nloc & 31))] = *(float4*)&acc[i][j];
                }
            }
        }
        __syncthreads();
#pragma unroll
        for (int u = 0; u < 8; u++) {
            int idx4 = u * 256 + t;
            int nloc = idx4 >> 5, c4 = idx4 & 31;
            float4 v = tb4[nloc * 32 + (c4 ^ (nloc & 31))];
            uint2 o;
            o.x = (u32)f2bf(v.x) | ((u32)f2bf(v.y) << 16);
            o.y = (u32)f2bf(v.z) | ((u32)f2bf(v.w) << 16);
            *(uint2*)&GTB[((size_t)bidx * DD + n0 + p * 64 + nloc) * LL + tbase + c4 * 4] = o;
        }
    }
}

// ---------------------------------------------------------------------------
// out = XC * Wv^T + bv where XC is computed ON THE FLY (R11 fusion of
// k_combine): A-tile row t = round_bf16( sum_j w_j * XB[(t - idx_j) & 2047] ).
// Replaces the A-side global_load_lds with 4 gathered b128 loads (XB is
// L3-resident; per j a wave reads 8 rows x 128 B chunks) + fp32 weighted sum
// + f2bf (bit-identical to the old k_combine) + one ds_write_b128 to the SAME
// LDS address the async copy used. Saves the 32 MB XC write + 32 MB read and
// the whole k_combine dispatch.
__global__ __launch_bounds__(256, 2) void k_gemm3(const u16* __restrict__ Ab,
                                                  const u16* __restrict__ Bm,
                                                  const float* __restrict__ wts,
                                                  const int* __restrict__ idxs,
                                                  const float* __restrict__ bv,
                                                  float* __restrict__ out) {
    __shared__ u16 smem[16384];
    u16* As = smem;
    u16* Bs = smem + 8192;
    int t = threadIdx.x;
    int wave = t >> 6, lane = t & 63;
    int l15 = lane & 15, l4 = lane >> 4;
    int qr = wave & 1, qc = wave >> 1;
    int m0 = blockIdx.x * 128, n0 = blockIdx.y * 128;
    int bb = m0 >> 11;               // batch
    int t0 = m0 & 2047;              // row base within batch

    float w0 = wts[bb * TOPK + 0], w1 = wts[bb * TOPK + 1];
    float w2 = wts[bb * TOPK + 2], w3 = wts[bb * TOPK + 3];
    int dx0 = idxs[bb * TOPK + 0], dx1 = idxs[bb * TOPK + 1];
    int dx2 = idxs[bb * TOPK + 2], dx3 = idxs[bb * TOPK + 3];

    f32x4 acc[4][4];
#pragma unroll
    for (int i = 0; i < 4; i++)
#pragma unroll
        for (int j = 0; j < 4; j++) acc[i][j] = (f32x4){0.f, 0.f, 0.f, 0.f};

    const u16* XBb = Ab + (size_t)bb * LL * DD;
    const u16* Bg = Bm + (size_t)DD * DD + (size_t)n0 * DD;
    int a_base = (qr * 64 + l15) * 64 + l4 * 8;
    int b_base = (qc * 64 + l15) * 64 + l4 * 8;

    for (int k0 = 0; k0 < DD; k0 += 64) {
        // B staging: async copy (unchanged)
#pragma unroll
        for (int n = 0; n < 4; n++) {
            int c = wave * 256 + n * 64 + lane;
            int row = c >> 3, col = (c & 7) * 8;
            gload16(Bg + (size_t)row * DD + k0 + col, (char*)Bs + (size_t)(wave * 256 + n * 64) * 16);
        }
        // A staging: fused weighted gather -> bf16 -> LDS
#pragma unroll
        for (int n = 0; n < 4; n++) {
            int c = wave * 256 + n * 64 + lane;
            int row = c >> 3, col = (c & 7) * 8;
            int tr = t0 + row;
            float af[8] = {0.f, 0.f, 0.f, 0.f, 0.f, 0.f, 0.f, 0.f};
#pragma unroll
            for (int j = 0; j < TOPK; j++) {
                int dxj = (j == 0) ? dx0 : (j == 1) ? dx1 : (j == 2) ? dx2 : dx3;
                float wj = (j == 0) ? w0 : (j == 1) ? w1 : (j == 2) ? w2 : w3;
                int sr = (tr - dxj) & (LL - 1);
                uint4 v = *(const uint4*)&XBb[(size_t)sr * DD + k0 + col];
                af[0] += wj * bf2f((u16)v.x);      af[1] += wj * bf2f((u16)(v.x >> 16));
                af[2] += wj * bf2f((u16)v.y);      af[3] += wj * bf2f((u16)(v.y >> 16));
                af[4] += wj * bf2f((u16)v.z);      af[5] += wj * bf2f((u16)(v.z >> 16));
                af[6] += wj * bf2f((u16)v.w);      af[7] += wj * bf2f((u16)(v.w >> 16));
            }
            uint4 o;
            o.x = (u32)f2bf(af[0]) | ((u32)f2bf(af[1]) << 16);
            o.y = (u32)f2bf(af[2]) | ((u32)f2bf(af[3]) << 16);
            o.z = (u32)f2bf(af[4]) | ((u32)f2bf(af[5]) << 16);
            o.w = (u32)f2bf(af[6]) | ((u32)f2bf(af[7]) << 16);
            *(uint4*)((char*)As + (size_t)c * 16) = o;
        }
        __syncthreads();
#pragma unroll
        for (int kk = 0; kk < 64; kk += 32) {
            bf16x8 af4[4], bq[4];
#pragma unroll
            for (int i = 0; i < 4; i++) af4[i] = *(const bf16x8*)(As + a_base + i * 1024 + kk);
#pragma unroll
            for (int j = 0; j < 4; j++) bq[j] = *(const bf16x8*)(Bs + b_base + j * 1024 + kk);
#pragma unroll
            for (int i = 0; i < 4; i++)
#pragma unroll
                for (int j = 0; j < 4; j++)
                    acc[i][j] = __builtin_amdgcn_mfma_f32_16x16x32_bf16(af4[i], bq[j], acc[i][j], 0, 0, 0);
        }
        __syncthreads();
    }

    float*  tb  = (float*)smem;
    float4* tb4 = (float4*)smem;
#pragma unroll
    for (int p = 0; p < 2; p++) {
        __syncthreads();
        if (qr == p) {
#pragma unroll
            for (int j = 0; j < 4; j++) {
                int nloc = qc * 64 + j * 16 + l15;
#pragma unroll
                for (int i = 0; i < 4; i++) {
#pragma unroll
                    for (int r = 0; r < 4; r++) {
                        int mloc = i * 16 + l4 * 4 + r;
                        int nc = ((nloc >> 2) ^ (mloc & 31)) << 2;
                        tb[mloc * 128 + nc + (nloc & 3)] = acc[i][j][r];
                    }
                }
            }
        }
        __syncthreads();
#pragma unroll
        for (int u = 0; u < 8; u++) {
            int idx4 = u * 256 + t;
            int mloc = idx4 >> 5, c4 = idx4 & 31;
            float4 v = tb4[mloc * 32 + (c4 ^ (mloc & 31))];
            float4 bias = *(const float4*)&bv[n0 + c4 * 4];
            v.x += bias.x; v.y += bias.y; v.z += bias.z; v.w += bias.w;
            *(float4*)&out[(size_t)(m0 + p * 64 + mloc) * DD + n0 + c4 * 4] = v;
        }
    }
}

// ---------------------------------------------------------------------------
// Per (b, 8-channel group): packed FFT of z = x_d + i*G_d. Fused radix-2 +
// first radix-4 in registers (R10-verified); 4-stage chain M=8..512 with a
// 64-entry twiddle table. LDS = 37360 B -> 4 blocks/CU.
__global__ __launch_bounds__(256) void k_fft(const u16* __restrict__ XTB,
                                             const u16* __restrict__ GTB,
                                             float* __restrict__ S) {
    __shared__ float2 lds[4670];      // b1[2303] | b2[2303] | twl64[64]
    float2* b1  = lds;
    float2* b2  = lds + 2303;
    float2* twl = lds + 4606;
    int tid = threadIdx.x;            // 0..255
    int grp = blockIdx.x;             // 0..63
    int b = blockIdx.y;

    // 64-entry table: twl[i] = W^(8i)  (covers M=8/32/128 stage jm values)
    if (tid < 64) {
        float sn, cs;
        sincosf(-6.283185307179586f / 2048.0f * (float)(8 * tid), &sn, &cs);
        twl[tid] = make_float2(cs, sn);
    }
    float2 tw;
    {
        float sn, cs;
        sincosf(-6.283185307179586f / 2048.0f * (float)tid, &sn, &cs);
        tw = make_float2(cs, sn);
    }
    const float2 Cm1 = make_float2(0.70710678118654752f, -0.70710678118654752f);
    const float2 Cm2 = make_float2(0.f, -1.f);
    const float2 Cm3 = make_float2(-0.70710678118654752f, -0.70710678118654752f);
    float2 Tm1 = cmul(tw, Cm1), Tm2 = cmul(tw, Cm2), Tm3 = cmul(tw, Cm3);
    float2 R1 = cmul(tw, tw);
    float2 R2 = cmul(R1, R1);
    float2 R3 = cmul(R1, R2);
    __syncthreads();

    float2 sr[4];
#pragma unroll
    for (int r = 0; r < 4; r++) sr[r] = make_float2(0.f, 0.f);
    float s1024 = 0.f;

    for (int c = 0; c < 8; c++) {
        int d = grp * 8 + c;
        const u16* xp = XTB + ((size_t)b * DD + d) * LL;
        const u16* gp = GTB + ((size_t)b * DD + d) * LL;
        float2 se0[4], se1[4];
#pragma unroll
        for (int m = 0; m < 4; m++) {
            int j = tid + 256 * m;
            float2 za = make_float2(bf2f(xp[j]), bf2f(gp[j]));
            float2 zb = make_float2(bf2f(xp[j + 1024]), bf2f(gp[j + 1024]));
            se0[m] = cadd(za, zb);
            float2 dz = csub(za, zb);
            se1[m] = (m == 0) ? cmul(dz, tw)
                   : (m == 1) ? cmul(dz, Tm1)
                   : (m == 2) ? cmul(dz, Tm2)
                              : cmul(dz, Tm3);
        }
        float2* wp = &b1[P(8 * tid)];
        {
            float2 t0 = cadd(se0[0], se0[2]), t1 = csub(se0[0], se0[2]);
            float2 t2 = cadd(se0[1], se0[3]), bd = csub(se0[1], se0[3]);
            float2 t3 = make_float2(bd.y, -bd.x);                 // SGN=+1
            wp[0] = cadd(t0, t2);
            wp[2] = cmul(cadd(t1, t3), R1);
            wp[4] = cmul(csub(t0, t2), R2);
            wp[6] = cmul(csub(t1, t3), R3);
        }
        {
            float2 t0 = cadd(se1[0], se1[2]), t1 = csub(se1[0], se1[2]);
            float2 t2 = cadd(se1[1], se1[3]), bd = csub(se1[1], se1[3]);
            float2 t3 = make_float2(bd.y, -bd.x);
            wp[1] = cadd(t0, t2);
            wp[3] = cmul(cadd(t1, t3), R1);
            wp[5] = cmul(csub(t0, t2), R2);
            wp[7] = cmul(csub(t1, t3), R3);
        }
        __syncthreads();
        radix4<8,   1, 256, 3>(b1, b2, twl, tid); __syncthreads();
        radix4<32,  1, 256, 3>(b2, b1, twl, tid); __syncthreads();
        radix4<128, 1, 256, 3>(b1, b2, twl, tid); __syncthreads();
        radix4<512, 1, 256, 3>(b2, b1, twl, tid); __syncthreads();
        // Result in b1. Hermitian split + accumulate S += Xf * conj(Gf).
#pragma unroll
        for (int r = 0; r < 4; r++) {
            int f = tid + 256 * r;
            float2 p = b1[P(f)];
            float2 q = b1[P((2048 - f) & 2047)];
            float ar = 0.5f * (p.x + q.x), ai = 0.5f * (p.y - q.y);
            float dr = p.x - q.x, di = p.y + q.y;
            float gr = 0.5f * di, gi = -0.5f * dr;
            sr[r].x += ar * gr + ai * gi;
            sr[r].y += ai * gr - ar * gi;
        }
        if (tid == 0) {
            float2 p = b1[P(1024)];
            s1024 += p.x * p.y;
        }
        __syncthreads();   // b1 reads done before next channel's load writes b1
    }
    float* Sg = S + (size_t)b * NF * 2;
#pragma unroll
    for (int r = 0; r < 4; r++) {
        int f = tid + 256 * r;
        atomicAdd(&Sg[2 * f], sr[r].x);
        atomicAdd(&Sg[2 * f + 1], sr[r].y);
    }
    if (tid == 0) {
        atomicAdd(&Sg[2048], s1024);
    }
}

// ---------------------------------------------------------------------------
// Per batch: inverse FFT (fused-r2 load of Hermitian-extended spectrum) ->
// mean_corr, top-4, softmax. 256 threads, verified 5-stage chain (TS=0).
__global__ __launch_bounds__(256) void k_topk(const float* __restrict__ S,
                                              float* __restrict__ wts,
                                              int* __restrict__ idxs) {
    __shared__ float2 lds[5118];
    float2* b1  = lds;
    float2* b2  = lds + 2303;
    float2* twl = lds + 4606;
    __shared__ float cv[2048];
    __shared__ float rv[256];
    __shared__ int ri[256];
    __shared__ float topv[TOPK];
    __shared__ int topi[TOPK];
    int tid = threadIdx.x;
    int b = blockIdx.x;
    const float* Sg = S + (size_t)b * NF * 2;

    // 512-entry inverse twiddle table
    for (int j = tid; j < 512; j += 256) {
        float sn, cs;
        sincosf(6.283185307179586f / 2048.0f * (float)j, &sn, &cs);
        twl[j] = make_float2(cs, sn);
    }
    __syncthreads();

    // fused Hermitian-extension load + radix-2 -> b1 (register twiddles)
#pragma unroll
    for (int h = 0; h < 2; h++) {
#pragma unroll
        for (int e = 0; e < 2; e++) {
            int j = 2 * tid + 512 * h + e;
            float sn, cs;
            sincosf(6.283185307179586f / 2048.0f * (float)j, &sn, &cs);   // inverse sign
            float2 T = make_float2(cs, sn);
            float2 zl = make_float2(Sg[2 * j], Sg[2 * j + 1]);            // j <= 1023
            int fh = j + 1024;
            int ms = 2048 - fh;                                           // mirror for fh>1024
            float2 zh = (fh == 1024) ? make_float2(Sg[2048], Sg[2049])
                                     : make_float2(Sg[2 * ms], -Sg[2 * ms + 1]);
            b1[P(2 * j)]     = cadd(zl, zh);
            b1[P(2 * j + 1)] = cmul(csub(zl, zh), T);
        }
    }
    __syncthreads();
    radix4<2,   -1, 256, 0>(b1, b2, twl, tid); __syncthreads();
    radix4<8,   -1, 256, 0>(b2, b1, twl, tid); __syncthreads();
    radix4<32,  -1, 256, 0>(b1, b2, twl, tid); __syncthreads();
    radix4<128, -1, 256, 0>(b2, b1, twl, tid); __syncthreads();
    radix4<512, -1, 256, 0>(b1, b2, twl, tid); __syncthreads();
    const float scale = 1.0f / ((float)LL * (float)DD);
    for (int f = tid; f < 2048; f += 256) cv[f] = b2[P(f)].x * scale;
    __syncthreads();
    for (int r = 0; r < TOPK; r++) {
        float best = -3.0e38f;
        int bi = 0x7fffffff;
        for (int f = tid; f < 2048; f += 256) {
            bool taken = false;
            for (int q = 0; q < r; q++) taken |= (topi[q] == f);
            float v = cv[f];
            if (!taken && (v > best || (v == best && f < bi))) { best = v; bi = f; }
        }
        rv[tid] = best; ri[tid] = bi;
        __syncthreads();
        for (int s = 128; s > 0; s >>= 1) {
            if (tid < s) {
                float v2 = rv[tid + s]; int i2 = ri[tid + s];
                if (v2 > rv[tid] || (v2 == rv[tid] && i2 < ri[tid])) { rv[tid] = v2; ri[tid] = i2; }
            }
            __syncthreads();
        }
        if (tid == 0) { topv[r] = rv[0]; topi[r] = ri[0]; }
        __syncthreads();
    }
    if (tid == 0) {
        float mx = topv[0];
        float e[TOPK], sum = 0.f;
        for (int k = 0; k < TOPK; k++) { e[k] = expf(topv[k] - mx); sum += e[k]; }
        for (int k = 0; k < TOPK; k++) {
            wts[b * TOPK + k] = e[k] / sum;
            idxs[b * TOPK + k] = topi[k];
        }
    }
}

// ---------------------------------------------------------------------------
extern "C" void kernel_launch(void* const* d_in, const int* in_sizes, int n_in,
                              void* d_out, int out_size, void* d_ws, size_t ws_size,
                              hipStream_t stream) {
    const float* x  = (const float*)d_in[0];
    const float* Wq = (const float*)d_in[1];
    const float* Wk = (const float*)d_in[3];
    const float* Wv = (const float*)d_in[5];
    const float* bv = (const float*)d_in[6];
    // bq, bk provably cancel (tau-independent shift; top-k & softmax shift-invariant)
    (void)in_sizes; (void)n_in; (void)out_size; (void)ws_size;

    float* ws  = (float*)d_ws;
    u16*   XB  = (u16*)(ws + OFF_XB);
    u16*   XTB = (u16*)(ws + OFF_XTB);
    u16*   GTB = (u16*)(ws + OFF_GTB);
    u16*   BM  = (u16*)(ws + OFF_BBM);
    float* S   = ws + OFF_S;
    float* wts = ws + OFF_W;
    int*   idx = (int*)(ws + OFF_I);
    float* out = (float*)d_out;

    k_pre<<<10560, 256, 0, stream>>>(x, Wq, Wk, Wv, XB, XTB, BM, S);
    k_gemm2<<<dim3((BB * LL) / 128, DD / 128), 256, 0, stream>>>(XB, BM, GTB);
    k_fft<<<dim3(64, BB), 256, 0, stream>>>(XTB, GTB, S);
    k_topk<<<BB, 256, 0, stream>>>(S, wts, idx);
    k_gemm3<<<dim3((BB * LL) / 128, DD / 128), 256, 0, stream>>>(XB, BM, wts, idx, bv, out);
}

// Round 12
// 304.385 us; speedup vs baseline: 1.1947x; 1.1947x over previous
//
#include <hip/hip_runtime.h>
#include <math.h>

typedef unsigned short u16;
typedef unsigned int   u32;
typedef __attribute__((ext_vector_type(8))) __bf16 bf16x8;
typedef __attribute__((ext_vector_type(4))) float  f32x4;

#define BB 16
#define LL 2048
#define DD 512
#define NF 1025
#define TOPK 4

// ws layout (float-unit offsets), total ~136 MB
static const size_t OFF_XB  = 0;                         // bf16 x row-major [B*L][D]
static const size_t OFF_XTB = OFF_XB  + 8388608;         // bf16 x transposed [B][D][L]
static const size_t OFF_GTB = OFF_XTB + 8388608;         // bf16 G transposed [B][D][L]
static const size_t OFF_XC  = OFF_GTB + 8388608;         // bf16 combined x [B*L][D]
static const size_t OFF_BBM = OFF_XC  + 8388608;         // bf16 Bmat [1024][512]: 0..511=M, 512..1023=Wv
static const size_t OFF_S   = OFF_BBM + 262144;          // spectra [B][NF][2]
static const size_t OFF_W   = OFF_S   + (size_t)BB * NF * 2;
static const size_t OFF_I   = OFF_W   + BB * TOPK;

__device__ __forceinline__ u16 f2bf(float f) {
    u32 u = __float_as_uint(f);
    return (u16)((u + 0x7fffu + ((u >> 16) & 1u)) >> 16);
}
__device__ __forceinline__ float bf2f(u16 h) {
    return __uint_as_float(((u32)h) << 16);
}
__device__ __forceinline__ void gload16(const void* g, void* l) {
    __builtin_amdgcn_global_load_lds((const __attribute__((address_space(1))) void*)g,
                                     (__attribute__((address_space(3))) void*)l, 16, 0, 0);
}
__device__ __forceinline__ float2 cmul(float2 u, float2 v) {
    return make_float2(u.x * v.x - u.y * v.y, u.x * v.y + u.y * v.x);
}
__device__ __forceinline__ float2 cadd(float2 u, float2 v) { return make_float2(u.x + v.x, u.y + v.y); }
__device__ __forceinline__ float2 csub(float2 u, float2 v) { return make_float2(u.x - v.x, u.y - v.y); }

// Bank-conflict-reducing padded index (1 pad per 8 float2).
__device__ __forceinline__ int P(int i) { return i + (i >> 3); }

// ---------------------------------------------------------------------------
// Radix-4 Stockham stage (R4/R5-verified math). NT = threads, TS = twiddle
// table shift (table holds W^{j<<TS}; all jm for the stages used are multiples
// of 1<<TS). M=512 has jm==0 -> identity, specialized.
template<int M, int SGN, int NT, int TS>
__device__ __forceinline__ void radix4(const float2* __restrict__ src,
                                       float2* __restrict__ dst,
                                       const float2* __restrict__ twl, int tid) {
#pragma unroll
    for (int r = 0; r < 512 / NT; r++) {
        int w = tid + NT * r;
        int k = w & (M - 1);
        int jm = w - k;
        float2 a = src[P(w)], b = src[P(w + 512)], c = src[P(w + 1024)], d = src[P(w + 1536)];
        float2 t0 = cadd(a, c), t1 = csub(a, c), t2 = cadd(b, d), bd = csub(b, d);
        float2 t3 = (SGN > 0) ? make_float2(bd.y, -bd.x)
                              : make_float2(-bd.y, bd.x);
        int o = 4 * jm + k;
        if (M == 512) {
            dst[P(o)]         = cadd(t0, t2);
            dst[P(o + M)]     = cadd(t1, t3);
            dst[P(o + 2 * M)] = csub(t0, t2);
            dst[P(o + 3 * M)] = csub(t1, t3);
        } else {
            float2 T1 = twl[jm >> TS];
            float2 T2 = cmul(T1, T1);
            float2 T3 = cmul(T1, T2);
            dst[P(o)]         = cadd(t0, t2);
            dst[P(o + M)]     = cmul(cadd(t1, t3), T1);
            dst[P(o + 2 * M)] = cmul(csub(t0, t2), T2);
            dst[P(o + 3 * M)] = cmul(csub(t1, t3), T3);
        }
    }
}

// ---------------------------------------------------------------------------
// Merged prologue (R8-proven; R9's split regressed +15us).
//   bid 0..63      : gemm1 M = Wq^T*Wk
//   bid 64..319    : cast Wv + zero S
//   bid 320..2367  : transpose x -> XTB (32d x 256t tiles)
//   bid 2368..10559: streaming cast x -> XB (linear)
__global__ __launch_bounds__(256) void k_pre(const float* __restrict__ x,
                                             const float* __restrict__ Wq,
                                             const float* __restrict__ Wk,
                                             const float* __restrict__ Wv,
                                             u16* __restrict__ xb,
                                             u16* __restrict__ xtb,
                                             u16* __restrict__ Bm,
                                             float* __restrict__ S) {
    __shared__ char sh[16768];
    int bid = blockIdx.x;
    int tid = threadIdx.x;
    if (bid < 64) {
        // ---- gemm1 branch: M = Wq^T * Wk -> bf16 rows 0..511 of Bmat
        int g = bid;
        float (*As)[68] = (float(*)[68])sh;
        float (*Bs)[68] = (float(*)[68])(sh + 4352);
        int tx = tid & 15, ty = tid >> 4;
        int m0 = (g & 7) * 64, n0 = (g >> 3) * 64;
        float acc[4][4] = {};
        for (int k0 = 0; k0 < DD; k0 += 16) {
#pragma unroll
            for (int r = 0; r < 4; r++) {
                As[ty][tx + 16 * r] = Wq[(size_t)(k0 + ty) * DD + m0 + tx + 16 * r];
                Bs[ty][tx + 16 * r] = Wk[(size_t)(k0 + ty) * DD + n0 + tx + 16 * r];
            }
            __syncthreads();
#pragma unroll
            for (int k = 0; k < 16; k++) {
                float4 a4 = *(const float4*)&As[k][ty * 4];
                float4 b4 = *(const float4*)&Bs[k][tx * 4];
                float a[4] = {a4.x, a4.y, a4.z, a4.w};
                float b[4] = {b4.x, b4.y, b4.z, b4.w};
#pragma unroll
                for (int i = 0; i < 4; i++)
#pragma unroll
                    for (int j = 0; j < 4; j++) acc[i][j] += a[i] * b[j];
            }
            __syncthreads();
        }
#pragma unroll
        for (int i = 0; i < 4; i++) {
            uint2 o;
            o.x = (u32)f2bf(acc[i][0]) | ((u32)f2bf(acc[i][1]) << 16);
            o.y = (u32)f2bf(acc[i][2]) | ((u32)f2bf(acc[i][3]) << 16);
            *(uint2*)&Bm[(size_t)(m0 + ty * 4 + i) * DD + n0 + tx * 4] = o;
        }
    } else if (bid < 320) {
        // ---- misc branch: cast Wv (rows 512..1023 of Bmat), zero S
        int g = bid - 64;                    // 0..255
        int i4 = g * 256 + tid;              // float4 index over 512*512
        float4 w = ((const float4*)Wv)[i4];
        ushort4 o;
        o.x = f2bf(w.x); o.y = f2bf(w.y); o.z = f2bf(w.z); o.w = f2bf(w.w);
        ((ushort4*)(Bm + DD * DD))[i4] = o;
        if (i4 < 8200)                       // 32800 floats = 8200 float4
            ((float4*)S)[i4] = make_float4(0.f, 0.f, 0.f, 0.f);
    } else if (bid < 2368) {
        // ---- transpose branch: x fp32 -> XTB bf16 [b][d][t], 32d x 256t tile.
        int tb = bid - 320;                  // 0..2047
        int bx = tb & 15;                    // d-tile (16 x 32)
        int by = (tb >> 4) & 7;              // t-tile (8 x 256)
        int bz = tb >> 7;                    // batch
        u32* tile32 = (u32*)sh;              // [32][131] u32 = 16768 B
        int tx = tid & 7, ty = tid >> 3;     // tx: d-quad, ty: 0..31
        int d0 = bx * 32, t0 = by * 256;
        const float* ip = x + ((size_t)bz * LL + t0) * DD + d0 + tx * 4;
        float4 va[4], vb[4];
#pragma unroll
        for (int ii = 0; ii < 4; ii++) {
            int h = ty + 32 * ii;
            va[ii] = *(const float4*)&ip[(size_t)(2 * h) * DD];
            vb[ii] = *(const float4*)&ip[(size_t)(2 * h + 1) * DD];
        }
#pragma unroll
        for (int ii = 0; ii < 4; ii++) {
            int h = ty + 32 * ii;
            u32 a0 = f2bf(va[ii].x), a1 = f2bf(va[ii].y), a2 = f2bf(va[ii].z), a3 = f2bf(va[ii].w);
            u32 b0 = f2bf(vb[ii].x), b1 = f2bf(vb[ii].y), b2 = f2bf(vb[ii].z), b3 = f2bf(vb[ii].w);
            tile32[(4 * tx + 0) * 131 + h] = a0 | (b0 << 16);
            tile32[(4 * tx + 1) * 131 + h] = a1 | (b1 << 16);
            tile32[(4 * tx + 2) * 131 + h] = a2 | (b2 << 16);
            tile32[(4 * tx + 3) * 131 + h] = a3 | (b3 << 16);
        }
        __syncthreads();
        u16* xtp = xtb + ((size_t)bz * DD + d0) * LL + t0;
#pragma unroll
        for (int u = 0; u < 4; u++) {
            int idx = u * 256 + tid;         // 0..1023
            int dr = idx >> 5;               // d row 0..31
            int ch = idx & 31;               // 16 B chunk within 512 B row
            const u32* rp = tile32 + dr * 131 + ch * 4;
            uint4 o = make_uint4(rp[0], rp[1], rp[2], rp[3]);
            *(uint4*)&xtp[(size_t)dr * LL + ch * 8] = o;
        }
    } else {
        // ---- streaming cast branch: x fp32 -> XB bf16, linear walk.
        size_t g = (size_t)(bid - 2368) * 256 + tid;   // uint4 index over XB
        const float4* x4 = (const float4*)x;
        float4 a = x4[2 * g], b = x4[2 * g + 1];
        uint4 o;
        o.x = (u32)f2bf(a.x) | ((u32)f2bf(a.y) << 16);
        o.y = (u32)f2bf(a.z) | ((u32)f2bf(a.w) << 16);
        o.z = (u32)f2bf(b.x) | ((u32)f2bf(b.y) << 16);
        o.w = (u32)f2bf(b.z) | ((u32)f2bf(b.w) << 16);
        ((uint4*)xb)[g] = o;
    }
}

// ---------------------------------------------------------------------------
// G = XB * M^T (bf16 MFMA), written transposed bf16 GTB[b][d][t].
__global__ __launch_bounds__(256, 2) void k_gemm2(const u16* __restrict__ Ab,
                                                  const u16* __restrict__ Bm,
                                                  u16* __restrict__ GTB) {
    __shared__ u16 smem[16384];
    u16* As = smem;
    u16* Bs = smem + 8192;
    int t = threadIdx.x;
    int wave = t >> 6, lane = t & 63;
    int l15 = lane & 15, l4 = lane >> 4;
    int qr = wave & 1, qc = wave >> 1;
    int m0 = blockIdx.x * 128, n0 = blockIdx.y * 128;

    f32x4 acc[4][4];
#pragma unroll
    for (int i = 0; i < 4; i++)
#pragma unroll
        for (int j = 0; j < 4; j++) acc[i][j] = (f32x4){0.f, 0.f, 0.f, 0.f};

    const u16* Ag = Ab + (size_t)m0 * DD;
    const u16* Bg = Bm + (size_t)n0 * DD;
    int a_base = (qr * 64 + l15) * 64 + l4 * 8;
    int b_base = (qc * 64 + l15) * 64 + l4 * 8;

    for (int k0 = 0; k0 < DD; k0 += 64) {
#pragma unroll
        for (int n = 0; n < 4; n++) {
            int c = wave * 256 + n * 64 + lane;
            int row = c >> 3, col = (c & 7) * 8;
            gload16(Ag + (size_t)row * DD + k0 + col, (char*)As + (size_t)(wave * 256 + n * 64) * 16);
            gload16(Bg + (size_t)row * DD + k0 + col, (char*)Bs + (size_t)(wave * 256 + n * 64) * 16);
        }
        __syncthreads();
#pragma unroll
        for (int kk = 0; kk < 64; kk += 32) {
            bf16x8 af[4], bq[4];
#pragma unroll
            for (int i = 0; i < 4; i++) af[i] = *(const bf16x8*)(As + a_base + i * 1024 + kk);
#pragma unroll
            for (int j = 0; j < 4; j++) bq[j] = *(const bf16x8*)(Bs + b_base + j * 1024 + kk);
#pragma unroll
            for (int i = 0; i < 4; i++)
#pragma unroll
                for (int j = 0; j < 4; j++)
                    acc[i][j] = __builtin_amdgcn_mfma_f32_16x16x32_bf16(af[i], bq[j], acc[i][j], 0, 0, 0);
        }
        __syncthreads();
    }

    // Epilogue: transposed bf16 write via swizzled LDS staging
    float4* tb4 = (float4*)smem;
    int bidx = m0 >> 11;
    int tbase = m0 & 2047;
#pragma unroll
    for (int p = 0; p < 2; p++) {
        __syncthreads();
        if (qc == p) {
#pragma unroll
            for (int j = 0; j < 4; j++) {
                int nloc = j * 16 + l15;
#pragma unroll
                for (int i = 0; i < 4; i++) {
                    int tq = qr * 16 + i * 4 + l4;
                    tb4[nloc * 32 + (tq ^ (nloc & 31))] = *(float4*)&acc[i][j];
                }
            }
        }
        __syncthreads();
#pragma unroll
        for (int u = 0; u < 8; u++) {
            int idx4 = u * 256 + t;
            int nloc = idx4 >> 5, c4 = idx4 & 31;
            float4 v = tb4[nloc * 32 + (c4 ^ (nloc & 31))];
            uint2 o;
            o.x = (u32)f2bf(v.x) | ((u32)f2bf(v.y) << 16);
            o.y = (u32)f2bf(v.z) | ((u32)f2bf(v.w) << 16);
            *(uint2*)&GTB[((size_t)bidx * DD + n0 + p * 64 + nloc) * LL + tbase + c4 * 4] = o;
        }
    }
}

// ---------------------------------------------------------------------------
// out = XC * Wv^T + bv (bf16 MFMA), row-major fp32 into d_out.
__global__ __launch_bounds__(256, 2) void k_gemm3(const u16* __restrict__ Ab,
                                                  const u16* __restrict__ Bm,
                                                  const float* __restrict__ bv,
                                                  float* __restrict__ out) {
    __shared__ u16 smem[16384];
    u16* As = smem;
    u16* Bs = smem + 8192;
    int t = threadIdx.x;
    int wave = t >> 6, lane = t & 63;
    int l15 = lane & 15, l4 = lane >> 4;
    int qr = wave & 1, qc = wave >> 1;
    int m0 = blockIdx.x * 128, n0 = blockIdx.y * 128;

    f32x4 acc[4][4];
#pragma unroll
    for (int i = 0; i < 4; i++)
#pragma unroll
        for (int j = 0; j < 4; j++) acc[i][j] = (f32x4){0.f, 0.f, 0.f, 0.f};

    const u16* Ag = Ab + (size_t)m0 * DD;
    const u16* Bg = Bm + (size_t)DD * DD + (size_t)n0 * DD;
    int a_base = (qr * 64 + l15) * 64 + l4 * 8;
    int b_base = (qc * 64 + l15) * 64 + l4 * 8;

    for (int k0 = 0; k0 < DD; k0 += 64) {
#pragma unroll
        for (int n = 0; n < 4; n++) {
            int c = wave * 256 + n * 64 + lane;
            int row = c >> 3, col = (c & 7) * 8;
            gload16(Ag + (size_t)row * DD + k0 + col, (char*)As + (size_t)(wave * 256 + n * 64) * 16);
            gload16(Bg + (size_t)row * DD + k0 + col, (char*)Bs + (size_t)(wave * 256 + n * 64) * 16);
        }
        __syncthreads();
#pragma unroll
        for (int kk = 0; kk < 64; kk += 32) {
            bf16x8 af[4], bq[4];
#pragma unroll
            for (int i = 0; i < 4; i++) af[i] = *(const bf16x8*)(As + a_base + i * 1024 + kk);
#pragma unroll
            for (int j = 0; j < 4; j++) bq[j] = *(const bf16x8*)(Bs + b_base + j * 1024 + kk);
#pragma unroll
            for (int i = 0; i < 4; i++)
#pragma unroll
                for (int j = 0; j < 4; j++)
                    acc[i][j] = __builtin_amdgcn_mfma_f32_16x16x32_bf16(af[i], bq[j], acc[i][j], 0, 0, 0);
        }
        __syncthreads();
    }

    float*  tb  = (float*)smem;
    float4* tb4 = (float4*)smem;
#pragma unroll
    for (int p = 0; p < 2; p++) {
        __syncthreads();
        if (qr == p) {
#pragma unroll
            for (int j = 0; j < 4; j++) {
                int nloc = qc * 64 + j * 16 + l15;
#pragma unroll
                for (int i = 0; i < 4; i++) {
#pragma unroll
                    for (int r = 0; r < 4; r++) {
                        int mloc = i * 16 + l4 * 4 + r;
                        int nc = ((nloc >> 2) ^ (mloc & 31)) << 2;
                        tb[mloc * 128 + nc + (nloc & 3)] = acc[i][j][r];
                    }
                }
            }
        }
        __syncthreads();
#pragma unroll
        for (int u = 0; u < 8; u++) {
            int idx4 = u * 256 + t;
            int mloc = idx4 >> 5, c4 = idx4 & 31;
            float4 v = tb4[mloc * 32 + (c4 ^ (mloc & 31))];
            float4 bias = *(const float4*)&bv[n0 + c4 * 4];
            v.x += bias.x; v.y += bias.y; v.z += bias.z; v.w += bias.w;
            *(float4*)&out[(size_t)(m0 + p * 64 + mloc) * DD + n0 + c4 * 4] = v;
        }
    }
}

// ---------------------------------------------------------------------------
// Per (b, 8-channel group): packed FFT of z = x_d + i*G_d. Fused radix-2 +
// first radix-4 in registers (R10-verified); 4-stage chain M=8..512 with a
// 64-entry twiddle table. LDS = 37360 B -> 4 blocks/CU.
__global__ __launch_bounds__(256) void k_fft(const u16* __restrict__ XTB,
                                             const u16* __restrict__ GTB,
                                             float* __restrict__ S) {
    __shared__ float2 lds[4670];      // b1[2303] | b2[2303] | twl64[64]
    float2* b1  = lds;
    float2* b2  = lds + 2303;
    float2* twl = lds + 4606;
    int tid = threadIdx.x;            // 0..255
    int grp = blockIdx.x;             // 0..63
    int b = blockIdx.y;

    // 64-entry table: twl[i] = W^(8i)  (covers M=8/32/128 stage jm values)
    if (tid < 64) {
        float sn, cs;
        sincosf(-6.283185307179586f / 2048.0f * (float)(8 * tid), &sn, &cs);
        twl[tid] = make_float2(cs, sn);
    }
    float2 tw;
    {
        float sn, cs;
        sincosf(-6.283185307179586f / 2048.0f * (float)tid, &sn, &cs);
        tw = make_float2(cs, sn);
    }
    const float2 Cm1 = make_float2(0.70710678118654752f, -0.70710678118654752f);
    const float2 Cm2 = make_float2(0.f, -1.f);
    const float2 Cm3 = make_float2(-0.70710678118654752f, -0.70710678118654752f);
    float2 Tm1 = cmul(tw, Cm1), Tm2 = cmul(tw, Cm2), Tm3 = cmul(tw, Cm3);
    float2 R1 = cmul(tw, tw);
    float2 R2 = cmul(R1, R1);
    float2 R3 = cmul(R1, R2);
    __syncthreads();

    float2 sr[4];
#pragma unroll
    for (int r = 0; r < 4; r++) sr[r] = make_float2(0.f, 0.f);
    float s1024 = 0.f;

    for (int c = 0; c < 8; c++) {
        int d = grp * 8 + c;
        const u16* xp = XTB + ((size_t)b * DD + d) * LL;
        const u16* gp = GTB + ((size_t)b * DD + d) * LL;
        float2 se0[4], se1[4];
#pragma unroll
        for (int m = 0; m < 4; m++) {
            int j = tid + 256 * m;
            float2 za = make_float2(bf2f(xp[j]), bf2f(gp[j]));
            float2 zb = make_float2(bf2f(xp[j + 1024]), bf2f(gp[j + 1024]));
            se0[m] = cadd(za, zb);
            float2 dz = csub(za, zb);
            se1[m] = (m == 0) ? cmul(dz, tw)
                   : (m == 1) ? cmul(dz, Tm1)
                   : (m == 2) ? cmul(dz, Tm2)
                              : cmul(dz, Tm3);
        }
        float2* wp = &b1[P(8 * tid)];
        {
            float2 t0 = cadd(se0[0], se0[2]), t1 = csub(se0[0], se0[2]);
            float2 t2 = cadd(se0[1], se0[3]), bd = csub(se0[1], se0[3]);
            float2 t3 = make_float2(bd.y, -bd.x);                 // SGN=+1
            wp[0] = cadd(t0, t2);
            wp[2] = cmul(cadd(t1, t3), R1);
            wp[4] = cmul(csub(t0, t2), R2);
            wp[6] = cmul(csub(t1, t3), R3);
        }
        {
            float2 t0 = cadd(se1[0], se1[2]), t1 = csub(se1[0], se1[2]);
            float2 t2 = cadd(se1[1], se1[3]), bd = csub(se1[1], se1[3]);
            float2 t3 = make_float2(bd.y, -bd.x);
            wp[1] = cadd(t0, t2);
            wp[3] = cmul(cadd(t1, t3), R1);
            wp[5] = cmul(csub(t0, t2), R2);
            wp[7] = cmul(csub(t1, t3), R3);
        }
        __syncthreads();
        radix4<8,   1, 256, 3>(b1, b2, twl, tid); __syncthreads();
        radix4<32,  1, 256, 3>(b2, b1, twl, tid); __syncthreads();
        radix4<128, 1, 256, 3>(b1, b2, twl, tid); __syncthreads();
        radix4<512, 1, 256, 3>(b2, b1, twl, tid); __syncthreads();
        // Result in b1. Hermitian split + accumulate S += Xf * conj(Gf).
#pragma unroll
        for (int r = 0; r < 4; r++) {
            int f = tid + 256 * r;
            float2 p = b1[P(f)];
            float2 q = b1[P((2048 - f) & 2047)];
            float ar = 0.5f * (p.x + q.x), ai = 0.5f * (p.y - q.y);
            float dr = p.x - q.x, di = p.y + q.y;
            float gr = 0.5f * di, gi = -0.5f * dr;
            sr[r].x += ar * gr + ai * gi;
            sr[r].y += ai * gr - ar * gi;
        }
        if (tid == 0) {
            float2 p = b1[P(1024)];
            s1024 += p.x * p.y;
        }
        __syncthreads();   // b1 reads done before next channel's load writes b1
    }
    float* Sg = S + (size_t)b * NF * 2;
#pragma unroll
    for (int r = 0; r < 4; r++) {
        int f = tid + 256 * r;
        atomicAdd(&Sg[2 * f], sr[r].x);
        atomicAdd(&Sg[2 * f + 1], sr[r].y);
    }
    if (tid == 0) {
        atomicAdd(&Sg[2048], s1024);
    }
}

// ---------------------------------------------------------------------------
// Per batch: inverse FFT (fused-r2 load of Hermitian-extended spectrum) ->
// mean_corr, top-4, softmax. 256 threads, verified 5-stage chain (TS=0).
__global__ __launch_bounds__(256) void k_topk(const float* __restrict__ S,
                                              float* __restrict__ wts,
                                              int* __restrict__ idxs) {
    __shared__ float2 lds[5118];
    float2* b1  = lds;
    float2* b2  = lds + 2303;
    float2* twl = lds + 4606;
    __shared__ float cv[2048];
    __shared__ float rv[256];
    __shared__ int ri[256];
    __shared__ float topv[TOPK];
    __shared__ int topi[TOPK];
    int tid = threadIdx.x;
    int b = blockIdx.x;
    const float* Sg = S + (size_t)b * NF * 2;

    // 512-entry inverse twiddle table
    for (int j = tid; j < 512; j += 256) {
        float sn, cs;
        sincosf(6.283185307179586f / 2048.0f * (float)j, &sn, &cs);
        twl[j] = make_float2(cs, sn);
    }
    __syncthreads();

    // fused Hermitian-extension load + radix-2 -> b1 (register twiddles)
#pragma unroll
    for (int h = 0; h < 2; h++) {
#pragma unroll
        for (int e = 0; e < 2; e++) {
            int j = 2 * tid + 512 * h + e;
            float sn, cs;
            sincosf(6.283185307179586f / 2048.0f * (float)j, &sn, &cs);   // inverse sign
            float2 T = make_float2(cs, sn);
            float2 zl = make_float2(Sg[2 * j], Sg[2 * j + 1]);            // j <= 1023
            int fh = j + 1024;
            int ms = 2048 - fh;                                           // mirror for fh>1024
            float2 zh = (fh == 1024) ? make_float2(Sg[2048], Sg[2049])
                                     : make_float2(Sg[2 * ms], -Sg[2 * ms + 1]);
            b1[P(2 * j)]     = cadd(zl, zh);
            b1[P(2 * j + 1)] = cmul(csub(zl, zh), T);
        }
    }
    __syncthreads();
    radix4<2,   -1, 256, 0>(b1, b2, twl, tid); __syncthreads();
    radix4<8,   -1, 256, 0>(b2, b1, twl, tid); __syncthreads();
    radix4<32,  -1, 256, 0>(b1, b2, twl, tid); __syncthreads();
    radix4<128, -1, 256, 0>(b2, b1, twl, tid); __syncthreads();
    radix4<512, -1, 256, 0>(b1, b2, twl, tid); __syncthreads();
    const float scale = 1.0f / ((float)LL * (float)DD);
    for (int f = tid; f < 2048; f += 256) cv[f] = b2[P(f)].x * scale;
    __syncthreads();
    for (int r = 0; r < TOPK; r++) {
        float best = -3.0e38f;
        int bi = 0x7fffffff;
        for (int f = tid; f < 2048; f += 256) {
            bool taken = false;
            for (int q = 0; q < r; q++) taken |= (topi[q] == f);
            float v = cv[f];
            if (!taken && (v > best || (v == best && f < bi))) { best = v; bi = f; }
        }
        rv[tid] = best; ri[tid] = bi;
        __syncthreads();
        for (int s = 128; s > 0; s >>= 1) {
            if (tid < s) {
                float v2 = rv[tid + s]; int i2 = ri[tid + s];
                if (v2 > rv[tid] || (v2 == rv[tid] && i2 < ri[tid])) { rv[tid] = v2; ri[tid] = i2; }
            }
            __syncthreads();
        }
        if (tid == 0) { topv[r] = rv[0]; topi[r] = ri[0]; }
        __syncthreads();
    }
    if (tid == 0) {
        float mx = topv[0];
        float e[TOPK], sum = 0.f;
        for (int k = 0; k < TOPK; k++) { e[k] = expf(topv[k] - mx); sum += e[k]; }
        for (int k = 0; k < TOPK; k++) {
            wts[b * TOPK + k] = e[k] / sum;
            idxs[b * TOPK + k] = topi[k];
        }
    }
}

// ---------------------------------------------------------------------------
// XC[b,l,:] = round_bf16( sum_k w_k * XB[b,(l-idx_k)&2047,:] )
// Vectorized: uint4 (8 bf16) per lane, 4 rows per 256-thread block.
// Same fp32-accumulate -> f2bf order as before (bit-identical output).
__global__ __launch_bounds__(256) void k_combine(const u16* __restrict__ XB,
                                                 const float* __restrict__ wts,
                                                 const int* __restrict__ idxs,
                                                 u16* __restrict__ XC) {
    int b = blockIdx.y;
    int t = threadIdx.x;
    int l = blockIdx.x * 4 + (t >> 6);        // row
    int c = (t & 63) * 8;                     // element col (16 B chunk)
    const u16* Xb = XB + (size_t)b * LL * DD;
    float w0 = wts[b * TOPK + 0], w1 = wts[b * TOPK + 1];
    float w2 = wts[b * TOPK + 2], w3 = wts[b * TOPK + 3];
    int dx0 = idxs[b * TOPK + 0], dx1 = idxs[b * TOPK + 1];
    int dx2 = idxs[b * TOPK + 2], dx3 = idxs[b * TOPK + 3];
    float af[8] = {0.f, 0.f, 0.f, 0.f, 0.f, 0.f, 0.f, 0.f};
#pragma unroll
    for (int j = 0; j < TOPK; j++) {
        int dxj = (j == 0) ? dx0 : (j == 1) ? dx1 : (j == 2) ? dx2 : dx3;
        float wj = (j == 0) ? w0 : (j == 1) ? w1 : (j == 2) ? w2 : w3;
        int sr = (l - dxj) & (LL - 1);
        uint4 v = *(const uint4*)&Xb[(size_t)sr * DD + c];
        af[0] += wj * bf2f((u16)v.x);  af[1] += wj * bf2f((u16)(v.x >> 16));
        af[2] += wj * bf2f((u16)v.y);  af[3] += wj * bf2f((u16)(v.y >> 16));
        af[4] += wj * bf2f((u16)v.z);  af[5] += wj * bf2f((u16)(v.z >> 16));
        af[6] += wj * bf2f((u16)v.w);  af[7] += wj * bf2f((u16)(v.w >> 16));
    }
    uint4 o;
    o.x = (u32)f2bf(af[0]) | ((u32)f2bf(af[1]) << 16);
    o.y = (u32)f2bf(af[2]) | ((u32)f2bf(af[3]) << 16);
    o.z = (u32)f2bf(af[4]) | ((u32)f2bf(af[5]) << 16);
    o.w = (u32)f2bf(af[6]) | ((u32)f2bf(af[7]) << 16);
    *(uint4*)&XC[(size_t)b * LL * DD + (size_t)l * DD + c] = o;
}

// ---------------------------------------------------------------------------
extern "C" void kernel_launch(void* const* d_in, const int* in_sizes, int n_in,
                              void* d_out, int out_size, void* d_ws, size_t ws_size,
                              hipStream_t stream) {
    const float* x  = (const float*)d_in[0];
    const float* Wq = (const float*)d_in[1];
    const float* Wk = (const float*)d_in[3];
    const float* Wv = (const float*)d_in[5];
    const float* bv = (const float*)d_in[6];
    // bq, bk provably cancel (tau-independent shift; top-k & softmax shift-invariant)
    (void)in_sizes; (void)n_in; (void)out_size; (void)ws_size;

    float* ws  = (float*)d_ws;
    u16*   XB  = (u16*)(ws + OFF_XB);
    u16*   XTB = (u16*)(ws + OFF_XTB);
    u16*   GTB = (u16*)(ws + OFF_GTB);
    u16*   XC  = (u16*)(ws + OFF_XC);
    u16*   BM  = (u16*)(ws + OFF_BBM);
    float* S   = ws + OFF_S;
    float* wts = ws + OFF_W;
    int*   idx = (int*)(ws + OFF_I);
    float* out = (float*)d_out;

    k_pre<<<10560, 256, 0, stream>>>(x, Wq, Wk, Wv, XB, XTB, BM, S);
    k_gemm2<<<dim3((BB * LL) / 128, DD / 128), 256, 0, stream>>>(XB, BM, GTB);
    k_fft<<<dim3(64, BB), 256, 0, stream>>>(XTB, GTB, S);
    k_topk<<<BB, 256, 0, stream>>>(S, wts, idx);
    k_combine<<<dim3(LL / 4, BB), 256, 0, stream>>>(XB, wts, idx, XC);
    k_gemm3<<<dim3((BB * LL) / 128, DD / 128), 256, 0, stream>>>(XC, BM, bv, out);
}